// Round 6
// baseline (185.332 us; speedup 1.0000x reference)
//
#include <hip/hip_runtime.h>

typedef __attribute__((ext_vector_type(8))) short bf16x8;
typedef __attribute__((ext_vector_type(4))) float f32x4;

#define WIDTH  2048
#define NHEADS 16
#define HDIM   128

__device__ __forceinline__ unsigned short f2bf(float f) {
  union { float f; unsigned int u; } v; v.f = f;
  unsigned int u = v.u;
  unsigned int r = (u + 0x7FFFu + ((u >> 16) & 1u)) >> 16;  // RNE
  return (unsigned short)r;
}

// Prep: transpose w_in/w_a [h][i][j] -> bf16 [h][j][i]; precompute 8*softplus(a_param).
__global__ __launch_bounds__(256) void prep_kernel(
    const float* __restrict__ w_in, const float* __restrict__ w_a,
    const float* __restrict__ a_param,
    unsigned short* __restrict__ wTin, unsigned short* __restrict__ wTa,
    float* __restrict__ sp8) {
  int tid = blockIdx.x * 256 + threadIdx.x;    // 0 .. 16*128*128-1
  int h   = tid >> 14;
  int rem = tid & 16383;
  int j   = rem >> 7;
  int i   = rem & 127;
  int src = (h << 14) + (i << 7) + j;
  wTin[tid] = f2bf(w_in[src]);
  wTa[tid]  = f2bf(w_a[src]);
  if (tid < WIDTH) {
    float v  = a_param[tid];
    float sp = (v > 20.0f) ? v : log1pf(__expf(v));
    sp8[tid] = 8.0f * sp;
  }
}

// Wave-independent design: no LDS, no barriers. Each wave = 32 batch rows x
// 64 output cols of one head. x panel (32x128) loaded into registers and
// converted to bf16 MFMA fragments; weights streamed from L2 (block's 4 waves
// share the same weight slice -> L1 hits). Epilogue re-reads x as f32 (L2-hot).
// bid bits: [6:0] row-group, [10:7] head, [11] col-half.
__global__ __launch_bounds__(256, 3) void rglru_kernel(
    const float* __restrict__ x, const float* __restrict__ state,
    const float* __restrict__ b_in, const float* __restrict__ b_a,
    const unsigned short* __restrict__ wTin, const unsigned short* __restrict__ wTa,
    const float* __restrict__ sp8, float* __restrict__ out) {
  const int t    = threadIdx.x;
  const int lane = t & 63;
  const int wid  = t >> 6;
  const int l15  = lane & 15;
  const int l4   = lane >> 4;

  const int bid  = blockIdx.x;
  const int h    = (bid >> 7) & 15;
  const int half = (bid >> 11) & 1;
  const int rb   = (bid & 127) * 4 + wid;     // 0..511, 32-row group

  const long row0 = (long)rb * 32;

  // ---- load x panel into registers: per (m,kk): 8 f32 at
  //      x[row0 + m*16 + l15][h*128 + kk*32 + l4*8] ----
  const float* xb = x + row0 * WIDTH + h * HDIM + l4 * 8;
  f32x4 xr[2][4][2];
#pragma unroll
  for (int m = 0; m < 2; ++m) {
    const float* xrow = xb + (long)(m * 16 + l15) * WIDTH;
#pragma unroll
    for (int kk = 0; kk < 4; ++kk) {
      xr[m][kk][0] = *reinterpret_cast<const f32x4*>(xrow + kk * 32);
      xr[m][kk][1] = *reinterpret_cast<const f32x4*>(xrow + kk * 32 + 4);
    }
  }
  // convert to bf16 fragments
  bf16x8 xf[2][4];
#pragma unroll
  for (int m = 0; m < 2; ++m)
#pragma unroll
    for (int kk = 0; kk < 4; ++kk) {
      union { bf16x8 v; unsigned short s[8]; } u;
#pragma unroll
      for (int e = 0; e < 4; ++e) {
        u.s[e]     = f2bf(xr[m][kk][0][e]);
        u.s[e + 4] = f2bf(xr[m][kk][1][e]);
      }
      xf[m][kk] = u.v;
    }

  // ---- MFMA: acc[m][n] over K=128; A = weight frag (out-col major), B = x frag ----
  f32x4 acc_in[2][4], acc_a[2][4];
#pragma unroll
  for (int m = 0; m < 2; ++m)
#pragma unroll
    for (int n = 0; n < 4; ++n) {
      acc_in[m][n] = (f32x4)(0.0f);
      acc_a[m][n]  = (f32x4)(0.0f);
    }

  const long wbase = ((long)(h * HDIM + half * 64 + l15)) * HDIM + l4 * 8;
  const unsigned short* wbi = wTin + wbase;
  const unsigned short* wba = wTa + wbase;

#pragma unroll
  for (int kk = 0; kk < 4; ++kk) {
    bf16x8 wfi[4], wfa[4];
#pragma unroll
    for (int n = 0; n < 4; ++n) {
      long o = (long)(n * 16) * HDIM + kk * 32;
      wfi[n] = *reinterpret_cast<const bf16x8*>(wbi + o);
      wfa[n] = *reinterpret_cast<const bf16x8*>(wba + o);
    }
#pragma unroll
    for (int m = 0; m < 2; ++m)
#pragma unroll
      for (int n = 0; n < 4; ++n) {
        acc_in[m][n] = __builtin_amdgcn_mfma_f32_16x16x32_bf16(
            wfi[n], xf[m][kk], acc_in[m][n], 0, 0, 0);
        acc_a[m][n] = __builtin_amdgcn_mfma_f32_16x16x32_bf16(
            wfa[n], xf[m][kk], acc_a[m][n], 0, 0, 0);
      }
  }

  // ---- epilogue: D col (lane&15) = batch row, D row (l4*4+reg) = out col ----
#pragma unroll
  for (int n = 0; n < 4; ++n) {
    int ch = half * 64 + n * 16 + l4 * 4;     // col within head
    int c  = h * HDIM + ch;                   // col within width
    f32x4 bi  = *reinterpret_cast<const f32x4*>(b_in + h * HDIM + ch);
    f32x4 bav = *reinterpret_cast<const f32x4*>(b_a + h * HDIM + ch);
    f32x4 sp  = *reinterpret_cast<const f32x4*>(sp8 + c);
#pragma unroll
    for (int m = 0; m < 2; ++m) {
      long off = (row0 + m * 16 + l15) * WIDTH + c;
      f32x4 xv = *reinterpret_cast<const f32x4*>(x + off);      // L1/L2-hot
      f32x4 sv = *reinterpret_cast<const f32x4*>(state + off);
      f32x4 o;
#pragma unroll
      for (int r = 0; r < 4; ++r) {
        float yin = acc_in[m][n][r] + bi[r];
        float ya  = acc_a[m][n][r] + bav[r];
        float gx = __builtin_amdgcn_rcpf(1.0f + __expf(-yin));
        float ga = __builtin_amdgcn_rcpf(1.0f + __expf(-ya));
        float av = __expf(-ga * sp[r]);
        float sc = __builtin_amdgcn_sqrtf(fmaxf(1.0f - av * av, 0.0f));
        o[r] = av * sv[r] + gx * xv[r] * sc;
      }
      *reinterpret_cast<f32x4*>(out + off) = o;
    }
  }
}

extern "C" void kernel_launch(void* const* d_in, const int* in_sizes, int n_in,
                              void* d_out, int out_size, void* d_ws, size_t ws_size,
                              hipStream_t stream) {
  const float* x       = (const float*)d_in[0];
  const float* state   = (const float*)d_in[1];
  const float* w_in    = (const float*)d_in[2];
  const float* b_in    = (const float*)d_in[3];
  const float* w_a     = (const float*)d_in[4];
  const float* b_a     = (const float*)d_in[5];
  const float* a_param = (const float*)d_in[6];
  float* out = (float*)d_out;

  unsigned short* wTin = (unsigned short*)d_ws;
  unsigned short* wTa  = wTin + NHEADS * HDIM * HDIM;
  float*          sp8  = (float*)(wTa + NHEADS * HDIM * HDIM);

  // prep: 16*128*128 = 262144 elements -> 1024 blocks
  hipLaunchKernelGGL(prep_kernel, dim3(1024), dim3(256), 0, stream,
                     w_in, w_a, a_param, wTin, wTa, sp8);

  // main: 16384 waves = 4096 blocks x 4 waves (32 rows x 64 cols each)
  hipLaunchKernelGGL(rglru_kernel, dim3(4096), dim3(256), 0, stream,
                     x, state, b_in, b_a, wTin, wTa, sp8, out);
}

// Round 7
// 117.429 us; speedup vs baseline: 1.5783x; 1.5783x over previous
//
#include <hip/hip_runtime.h>

typedef __attribute__((ext_vector_type(8))) short bf16x8;
typedef __attribute__((ext_vector_type(4))) float f32x4;
typedef __attribute__((ext_vector_type(4))) unsigned short u16x4;

#define WIDTH  2048
#define NHEADS 16
#define HDIM   128
#define BM     64
#define TPB    8   // tiles per block (consecutive row-groups, same head)

__device__ __forceinline__ unsigned short f2bf(float f) {
  union { float f; unsigned int u; } v; v.f = f;
  unsigned int u = v.u;
  unsigned int r = (u + 0x7FFFu + ((u >> 16) & 1u)) >> 16;  // RNE
  return (unsigned short)r;
}

__device__ __forceinline__ float bf2f(unsigned short s) {
  union { unsigned int u; float f; } v;
  v.u = ((unsigned int)s) << 16;
  return v.f;
}

// Prep: transpose w_in/w_a [h][i][j] -> bf16 [h][j][i]; precompute 8*softplus(a_param).
__global__ __launch_bounds__(256) void prep_kernel(
    const float* __restrict__ w_in, const float* __restrict__ w_a,
    const float* __restrict__ a_param,
    unsigned short* __restrict__ wTin, unsigned short* __restrict__ wTa,
    float* __restrict__ sp8) {
  int tid = blockIdx.x * 256 + threadIdx.x;    // 0 .. 16*128*128-1
  int h   = tid >> 14;
  int rem = tid & 16383;
  int j   = rem >> 7;
  int i   = rem & 127;
  int src = (h << 14) + (i << 7) + j;
  wTin[tid] = f2bf(w_in[src]);
  wTa[tid]  = f2bf(w_a[src]);
  if (tid < WIDTH) {
    float v  = a_param[tid];
    float sp = (v > 20.0f) ? v : log1pf(__expf(v));
    sp8[tid] = 8.0f * sp;
  }
}

// Persistent pipelined: block = 1 head x 8 consecutive 64-row tiles.
// Double-buffered LDS; next tile's x loads issued right after the (raw)
// barrier so HBM requests stay continuously in flight. Raw s_barrier +
// lgkmcnt(0) avoids __syncthreads' vmcnt(0) drain of the prefetch/stores.
__global__ __launch_bounds__(256, 2) void rglru_kernel(
    const float* __restrict__ x, const float* __restrict__ state,
    const float* __restrict__ b_in, const float* __restrict__ b_a,
    const unsigned short* __restrict__ wTin, const unsigned short* __restrict__ wTa,
    const float* __restrict__ sp8, float* __restrict__ out) {
  __shared__ unsigned short xs[2][BM * HDIM];  // 2 x 16 KB, XOR-swizzled bf16

  const int bid  = blockIdx.x;
  const int h    = bid & (NHEADS - 1);
  const int rg0  = (bid >> 4) * TPB;          // first row-group (64-row units)
  const int t    = threadIdx.x;
  const int lane = t & 63;
  const int wid  = t >> 6;
  const int l15  = lane & 15;
  const int l4   = lane >> 4;

  const int r_  = t >> 5;    // stage: row within 8-row stripe
  const int c4_ = t & 31;    // stage: float4 index within row

  const float* xbase = x + h * HDIM;
  f32x4 xa[8];

  // issue stage loads for tile tt into xa regs
  auto issue = [&](int tt) {
    long row0 = (long)(rg0 + tt) * BM;
#pragma unroll
    for (int it = 0; it < 8; ++it) {
      int r = it * 8 + r_;
      xa[it] = *reinterpret_cast<const f32x4*>(
          xbase + (row0 + r) * WIDTH + c4_ * 4);
    }
  };
  // convert + swizzled ds_write into buffer `buf`
  auto commit = [&](int buf) {
#pragma unroll
    for (int it = 0; it < 8; ++it) {
      int r = it * 8 + r_;
      uint2 p;
      p.x = (unsigned int)f2bf(xa[it][0]) | ((unsigned int)f2bf(xa[it][1]) << 16);
      p.y = (unsigned int)f2bf(xa[it][2]) | ((unsigned int)f2bf(xa[it][3]) << 16);
      int off = (r * 256 + c4_ * 8) ^ ((r & 7) << 4);
      *reinterpret_cast<uint2*>(reinterpret_cast<char*>(xs[buf]) + off) = p;
    }
  };

  // per-block constants (same head for all tiles)
  const unsigned short* wbin = wTin + ((h * HDIM + wid * 32) * HDIM);
  const unsigned short* wba  = wTa  + ((h * HDIM + wid * 32) * HDIM);
  f32x4 bi4[2], ba4[2], sp4[2];
#pragma unroll
  for (int n = 0; n < 2; ++n) {
    int colh0 = wid * 32 + n * 16 + l4 * 4;
    bi4[n] = *reinterpret_cast<const f32x4*>(b_in + h * HDIM + colh0);
    ba4[n] = *reinterpret_cast<const f32x4*>(b_a + h * HDIM + colh0);
    sp4[n] = *reinterpret_cast<const f32x4*>(sp8 + h * HDIM + colh0);
  }

  issue(0);

  for (int tt = 0; tt < TPB; ++tt) {
    const int buf = tt & 1;
    commit(buf);
    asm volatile("s_waitcnt lgkmcnt(0)" ::: "memory");
    __builtin_amdgcn_s_barrier();
    __builtin_amdgcn_sched_barrier(0);

    if (tt + 1 < TPB) issue(tt + 1);   // prefetch next tile (overlaps compute)

    const long row0 = (long)(rg0 + tt) * BM;

    // ---- MFMA: acc[m][n]; m = batch-row frag, n = col frag ----
    f32x4 acc_in[4][2], acc_a[4][2];
#pragma unroll
    for (int m = 0; m < 4; ++m)
#pragma unroll
      for (int n = 0; n < 2; ++n) {
        acc_in[m][n] = (f32x4)(0.0f);
        acc_a[m][n]  = (f32x4)(0.0f);
      }

#pragma unroll
    for (int kk = 0; kk < 4; ++kk) {
      bf16x8 xfr[4];
#pragma unroll
      for (int m = 0; m < 4; ++m) {
        int row  = m * 16 + l15;
        int boff = (row * 256 + kk * 64 + l4 * 16) ^ ((row & 7) << 4);
        xfr[m] = *reinterpret_cast<const bf16x8*>(
            reinterpret_cast<const char*>(xs[buf]) + boff);
      }
      bf16x8 win[2], wa[2];
#pragma unroll
      for (int n = 0; n < 2; ++n) {
        int widx = (n * 16 + l15) * HDIM + kk * 32 + l4 * 8;
        win[n] = *reinterpret_cast<const bf16x8*>(wbin + widx);
        wa[n]  = *reinterpret_cast<const bf16x8*>(wba + widx);
      }
#pragma unroll
      for (int m = 0; m < 4; ++m)
#pragma unroll
        for (int n = 0; n < 2; ++n) {
          acc_in[m][n] = __builtin_amdgcn_mfma_f32_16x16x32_bf16(
              win[n], xfr[m], acc_in[m][n], 0, 0, 0);
          acc_a[m][n] = __builtin_amdgcn_mfma_f32_16x16x32_bf16(
              wa[n], xfr[m], acc_a[m][n], 0, 0, 0);
        }
    }

    // ---- preload state for this tile (ILP burst, hides HBM latency) ----
    f32x4 sv[2][4];
#pragma unroll
    for (int n = 0; n < 2; ++n) {
      int colh0 = wid * 32 + n * 16 + l4 * 4;
#pragma unroll
      for (int m = 0; m < 4; ++m) {
        long off = (row0 + m * 16 + l15) * WIDTH + h * HDIM + colh0;
        sv[n][m] = *reinterpret_cast<const f32x4*>(state + off);
      }
    }

    // ---- epilogue ----
#pragma unroll
    for (int n = 0; n < 2; ++n) {
      int colh0 = wid * 32 + n * 16 + l4 * 4;
      f32x4 bi = bi4[n], bav = ba4[n], sp = sp4[n];
#pragma unroll
      for (int m = 0; m < 4; ++m) {
        int lrow = m * 16 + l15;
        long off = (row0 + lrow) * WIDTH + h * HDIM + colh0;
        int xoff = (lrow * 256 + colh0 * 2) ^ ((lrow & 7) << 4);
        u16x4 xb = *reinterpret_cast<const u16x4*>(
            reinterpret_cast<const char*>(xs[buf]) + xoff);
        f32x4 o;
#pragma unroll
        for (int r = 0; r < 4; ++r) {
          float yin = acc_in[m][n][r] + bi[r];
          float ya  = acc_a[m][n][r] + bav[r];
          float gx = __builtin_amdgcn_rcpf(1.0f + __expf(-yin));
          float ga = __builtin_amdgcn_rcpf(1.0f + __expf(-ya));
          float av = __expf(-ga * sp[r]);
          float sc = sqrtf(fmaxf(1.0f - av * av, 0.0f));
          o[r] = av * sv[n][m][r] + gx * bf2f(xb[r]) * sc;
        }
        *reinterpret_cast<f32x4*>(out + off) = o;
      }
    }
  }
}

extern "C" void kernel_launch(void* const* d_in, const int* in_sizes, int n_in,
                              void* d_out, int out_size, void* d_ws, size_t ws_size,
                              hipStream_t stream) {
  const float* x       = (const float*)d_in[0];
  const float* state   = (const float*)d_in[1];
  const float* w_in    = (const float*)d_in[2];
  const float* b_in    = (const float*)d_in[3];
  const float* w_a     = (const float*)d_in[4];
  const float* b_a     = (const float*)d_in[5];
  const float* a_param = (const float*)d_in[6];
  float* out = (float*)d_out;

  unsigned short* wTin = (unsigned short*)d_ws;
  unsigned short* wTa  = wTin + NHEADS * HDIM * HDIM;
  float*          sp8  = (float*)(wTa + NHEADS * HDIM * HDIM);

  // prep: 16*128*128 = 262144 elements -> 1024 blocks
  hipLaunchKernelGGL(prep_kernel, dim3(1024), dim3(256), 0, stream,
                     w_in, w_a, a_param, wTin, wTa, sp8);

  // main: 4096 tiles / TPB = 512 blocks (2 per CU, exactly balanced)
  hipLaunchKernelGGL(rglru_kernel, dim3(4096 / TPB), dim3(256), 0, stream,
                     x, state, b_in, b_a, wTin, wTa, sp8, out);
}